// Round 10
// baseline (493.143 us; speedup 1.0000x reference)
//
#include <hip/hip_runtime.h>

#define NEMB 1024
#define NH 16
#define HD 64
#define TT 2048
#define BTOT 4096  // B*T

typedef unsigned short u16;
typedef __bf16 bf16_t;
typedef bf16_t bf16x8 __attribute__((ext_vector_type(8)));
typedef float f32x4 __attribute__((ext_vector_type(4)));
typedef u16 u16x4 __attribute__((ext_vector_type(4)));

typedef const __attribute__((address_space(1))) void* gvp;
typedef __attribute__((address_space(3))) void* lvp;

static __device__ __forceinline__ u16 f2bf(float f) {
  unsigned u = __builtin_bit_cast(unsigned, f);
  u += 0x7fffu + ((u >> 16) & 1u);
  return (u16)(u >> 16);
}

// ---------------- fp32 -> bf16 (no transpose) ----------------
__global__ void cvt_bf16_k(const float* __restrict__ in, u16* __restrict__ out, int n4) {
  int i = blockIdx.x * blockDim.x + threadIdx.x;
  if (i >= n4) return;
  float4 f = ((const float4*)in)[i];
  u16x4 o = { f2bf(f.x), f2bf(f.y), f2bf(f.z), f2bf(f.w) };
  ((u16x4*)out)[i] = o;
}

// ---------------- fp32 [R][C] -> bf16 [C][R] ----------------
__global__ void transpose_cvt_k(const float* __restrict__ in, u16* __restrict__ out, int R, int C) {
  __shared__ float tile[32][33];
  int bx = blockIdx.x, by = blockIdx.y;
  int tx = threadIdx.x, ty = threadIdx.y;
  #pragma unroll
  for (int j = 0; j < 32; j += 8)
    tile[ty + j][tx] = in[(size_t)(by * 32 + ty + j) * C + bx * 32 + tx];
  __syncthreads();
  #pragma unroll
  for (int j = 0; j < 32; j += 8)
    out[(size_t)(bx * 32 + ty + j) * R + by * 32 + tx] = f2bf(tile[tx][ty + j]);
}

// ---------------- GEMM: C = A[M,K] * Bt[N,K]^T + bias, fused epilogues ----------------
// EPI 0: QKV -> scatter q[b,h,t,d], k[b,h,t,d], vt[b,h,d,t] (bf16)
// EPI 1: bias + relu -> bf16 o0[M,N]
// EPI 2: bias + residual(res fp32) -> fp32 outf[M,N]
template<int EPI>
__global__ void gemm_bt(const u16* __restrict__ A, const u16* __restrict__ Bt,
                        const float* __restrict__ bias, int M, int N, int K,
                        const float* __restrict__ res, float* __restrict__ outf,
                        u16* __restrict__ o0, u16* __restrict__ o1, u16* __restrict__ o2)
{
  __shared__ u16 As[128 * 32];
  __shared__ u16 Bs[128 * 32];
  const int tid = threadIdx.x;
  const int wave = tid >> 6, lane = tid & 63;
  const int l16 = lane & 15, lq = lane >> 4;
  const int row0 = blockIdx.x * 128, col0 = blockIdx.y * 128;
  const int wm = (wave >> 1) * 64, wn = (wave & 1) * 64;
  f32x4 acc[4][4] = {};

  for (int k0 = 0; k0 < K; k0 += 32) {
    #pragma unroll
    for (int c = 0; c < 2; ++c) {
      int li = c * 256 + wave * 64 + lane;
      const u16* ga = A  + (size_t)(row0 + (li >> 2)) * K + k0 + (li & 3) * 8;
      const u16* gb = Bt + (size_t)(col0 + (li >> 2)) * K + k0 + (li & 3) * 8;
      __builtin_amdgcn_global_load_lds((gvp)ga, (lvp)&As[(c * 256 + wave * 64) * 8], 16, 0, 0);
      __builtin_amdgcn_global_load_lds((gvp)gb, (lvp)&Bs[(c * 256 + wave * 64) * 8], 16, 0, 0);
    }
    __syncthreads();
    bf16x8 af[4], bfr[4];
    #pragma unroll
    for (int i = 0; i < 4; ++i) af[i]  = *(const bf16x8*)&As[(wm + i * 16 + l16) * 32 + lq * 8];
    #pragma unroll
    for (int j = 0; j < 4; ++j) bfr[j] = *(const bf16x8*)&Bs[(wn + j * 16 + l16) * 32 + lq * 8];
    #pragma unroll
    for (int i = 0; i < 4; ++i)
      #pragma unroll
      for (int j = 0; j < 4; ++j)
        acc[i][j] = __builtin_amdgcn_mfma_f32_16x16x32_bf16(af[i], bfr[j], acc[i][j], 0, 0, 0);
    __syncthreads();
  }

  #pragma unroll
  for (int i = 0; i < 4; ++i)
    #pragma unroll
    for (int j = 0; j < 4; ++j)
      #pragma unroll
      for (int r = 0; r < 4; ++r) {
        int grow = row0 + wm + i * 16 + lq * 4 + r;
        int gcol = col0 + wn + j * 16 + l16;
        float v = acc[i][j][r] + bias[gcol];
        if constexpr (EPI == 0) {
          int b = grow >> 11, t = grow & 2047;
          int sec = gcol >> 10, rem = gcol & 1023;
          int h = rem >> 6, d = rem & 63;
          u16 bits = f2bf(v);
          size_t bh = (size_t)(b * NH + h);
          if (sec == 0)      o0[(bh * TT + t) * HD + d] = bits;
          else if (sec == 1) o1[(bh * TT + t) * HD + d] = bits;
          else               o2[(bh * HD + d) * TT + t] = bits;
        } else if constexpr (EPI == 1) {
          v = fmaxf(v, 0.f);
          o0[(size_t)grow * N + gcol] = f2bf(v);
        } else {
          size_t idx = (size_t)grow * N + gcol;
          outf[idx] = v + res[idx];
        }
      }
}

// ---------------- flash attention + residual ----------------
// grid: 1024 blocks (1-D, XCD-swizzled), 256 threads = 4 waves, 16 q-rows/wave.
// Swizzle: xcd = id&7 owns heads [xcd*4, xcd*4+4) -> K/V (2 MB) stays in that
// XCD's 4 MB L2. Within an XCD, longest q-tiles dispatch first.
__global__ void __launch_bounds__(256, 4)
attn_k(const u16* __restrict__ qb, const u16* __restrict__ kb,
       const u16* __restrict__ vtb, const float* __restrict__ x,
       float* __restrict__ xres, u16* __restrict__ xresbf)
{
  __shared__ u16 P[4][16 * 72];  // per-wave P tile [16 rows][stride 72 u16]
  const int id = blockIdx.x;
  const int xcd = id & 7, r8 = id >> 3;
  const int bh = xcd * 4 + (r8 >> 5);
  const int xq = 31 - (r8 & 31);           // longest-first within XCD
  const int b = bh >> 4, h = bh & 15;
  const int tid = threadIdx.x, wave = tid >> 6, lane = tid & 63;
  const int l16 = lane & 15, lq = lane >> 4;
  const u16* qh = qb + (size_t)bh * TT * HD;
  const u16* kh = kb + (size_t)bh * TT * HD;
  const u16* vh = vtb + (size_t)bh * HD * TT;
  const int q0 = (xq * 4 + wave) * 16;

  bf16x8 qf[2];
  #pragma unroll
  for (int kd = 0; kd < 2; ++kd)
    qf[kd] = *(const bf16x8*)&qh[(q0 + l16) * HD + kd * 32 + lq * 8];

  f32x4 oacc[4] = {};
  float mrow[4], lrow[4];
  #pragma unroll
  for (int r = 0; r < 4; ++r) { mrow[r] = -1e30f; lrow[r] = 0.f; }

  const int nkv = (q0 >> 6) + 1;
  u16* Pw = P[wave];

  for (int kv = 0; kv < nkv; ++kv) {
    const int kv0 = kv * 64;
    const bool diag = (kv0 + 63 > q0);

    // QK^T: batch all 8 K-fragment loads, then 8 MFMA
    bf16x8 kf[8];
    #pragma unroll
    for (int n = 0; n < 4; ++n)
      #pragma unroll
      for (int kd = 0; kd < 2; ++kd)
        kf[n * 2 + kd] = *(const bf16x8*)&kh[(kv0 + n * 16 + l16) * HD + kd * 32 + lq * 8];
    f32x4 sacc[4] = {};
    #pragma unroll
    for (int n = 0; n < 4; ++n)
      #pragma unroll
      for (int kd = 0; kd < 2; ++kd)
        sacc[n] = __builtin_amdgcn_mfma_f32_16x16x32_bf16(qf[kd], kf[n * 2 + kd], sacc[n], 0, 0, 0);

    // V first half issued early: latency hides under softmax + P round-trip
    bf16x8 vf0[4];
    #pragma unroll
    for (int nd = 0; nd < 4; ++nd)
      vf0[nd] = *(const bf16x8*)&vh[(nd * 16 + l16) * TT + kv0 + lq * 8];

    // online softmax, 4 rows per lane-quad (row = lq*4+r), cols spread over l16
    #pragma unroll
    for (int r = 0; r < 4; ++r) {
      const int qr = q0 + lq * 4 + r;
      float rmax = -1e30f;
      #pragma unroll
      for (int n = 0; n < 4; ++n) {
        float s = sacc[n][r] * 0.125f;
        if (diag && (kv0 + n * 16 + l16) > qr) s = -1e30f;
        sacc[n][r] = s;
        rmax = fmaxf(rmax, s);
      }
      #pragma unroll
      for (int off = 1; off < 16; off <<= 1)
        rmax = fmaxf(rmax, __shfl_xor(rmax, off, 64));
      const float mold = mrow[r];
      const float mnew = fmaxf(mold, rmax);
      const float scl = __expf(mold - mnew);
      float rsum = 0.f;
      #pragma unroll
      for (int n = 0; n < 4; ++n) {
        float p = __expf(sacc[n][r] - mnew);
        sacc[n][r] = p;
        rsum += p;
      }
      #pragma unroll
      for (int off = 1; off < 16; off <<= 1)
        rsum += __shfl_xor(rsum, off, 64);
      mrow[r] = mnew;
      lrow[r] = lrow[r] * scl + rsum;
      #pragma unroll
      for (int nd = 0; nd < 4; ++nd) oacc[nd][r] *= scl;
    }

    // P -> LDS (row-major, stride 72 u16)
    #pragma unroll
    for (int n = 0; n < 4; ++n)
      #pragma unroll
      for (int r = 0; r < 4; ++r)
        Pw[(lq * 4 + r) * 72 + n * 16 + l16] = f2bf(sacc[n][r]);

    // V second half
    bf16x8 vf1[4];
    #pragma unroll
    for (int nd = 0; nd < 4; ++nd)
      vf1[nd] = *(const bf16x8*)&vh[(nd * 16 + l16) * TT + kv0 + 32 + lq * 8];

    // PV
    bf16x8 pf0 = *(const bf16x8*)&Pw[l16 * 72 + lq * 8];
    #pragma unroll
    for (int nd = 0; nd < 4; ++nd)
      oacc[nd] = __builtin_amdgcn_mfma_f32_16x16x32_bf16(pf0, vf0[nd], oacc[nd], 0, 0, 0);
    bf16x8 pf1 = *(const bf16x8*)&Pw[l16 * 72 + 32 + lq * 8];
    #pragma unroll
    for (int nd = 0; nd < 4; ++nd)
      oacc[nd] = __builtin_amdgcn_mfma_f32_16x16x32_bf16(pf1, vf1[nd], oacc[nd], 0, 0, 0);
  }

  #pragma unroll
  for (int r = 0; r < 4; ++r) {
    const float inv = 1.f / lrow[r];
    const int t = q0 + lq * 4 + r;
    const size_t rowbase = ((size_t)b * TT + t) * NEMB + h * HD;
    #pragma unroll
    for (int nd = 0; nd < 4; ++nd) {
      size_t idx = rowbase + nd * 16 + l16;
      float v = oacc[nd][r] * inv + x[idx];
      xres[idx] = v;
      xresbf[idx] = f2bf(v);
    }
  }
}

extern "C" void kernel_launch(void* const* d_in, const int* in_sizes, int n_in,
                              void* d_out, int out_size, void* d_ws, size_t ws_size,
                              hipStream_t stream) {
  const float* x    = (const float*)d_in[0];
  const float* Wqkv = (const float*)d_in[1];
  const float* bqkv = (const float*)d_in[2];
  const float* W1   = (const float*)d_in[3];
  const float* b1   = (const float*)d_in[4];
  const float* W2   = (const float*)d_in[5];
  const float* b2   = (const float*)d_in[6];
  float* out = (float*)d_out;

  char* ws = (char*)d_ws;
  u16* x_bf   = (u16*)(ws);                         // 4096*1024
  u16* wqkvt  = (u16*)(ws + 8388608);               // 3072*1024
  u16* w1t    = (u16*)(ws + 14680064);              // 4096*1024
  u16* w2t    = (u16*)(ws + 23068672);              // 1024*4096
  u16* qbuf   = (u16*)(ws + 31457280);              // 2*16*2048*64
  u16* kbuf   = (u16*)(ws + 39845888);
  u16* vtbuf  = (u16*)(ws + 48234496);
  float* xres = (float*)(ws + 56623104);            // 4096*1024 fp32
  u16* xresbf = (u16*)(ws + 73400320);              // 4096*1024
  u16* hbuf   = (u16*)(ws + 81788928);              // 4096*4096

  // conversions
  cvt_bf16_k<<<4096, 256, 0, stream>>>(x, x_bf, 1048576);
  transpose_cvt_k<<<dim3(96, 32),  dim3(32, 8), 0, stream>>>(Wqkv, wqkvt, 1024, 3072);
  transpose_cvt_k<<<dim3(128, 32), dim3(32, 8), 0, stream>>>(W1, w1t, 1024, 4096);
  transpose_cvt_k<<<dim3(32, 128), dim3(32, 8), 0, stream>>>(W2, w2t, 4096, 1024);

  // QKV projection
  gemm_bt<0><<<dim3(32, 24), 256, 0, stream>>>(x_bf, wqkvt, bqkv, BTOT, 3 * NEMB, NEMB,
                                               nullptr, nullptr, qbuf, kbuf, vtbuf);
  // attention + residual
  attn_k<<<1024, 256, 0, stream>>>(qbuf, kbuf, vtbuf, x, xres, xresbf);
  // MLP
  gemm_bt<1><<<dim3(32, 32), 256, 0, stream>>>(xresbf, w1t, b1, BTOT, 4 * NEMB, NEMB,
                                               nullptr, nullptr, hbuf, nullptr, nullptr);
  gemm_bt<2><<<dim3(32, 8), 256, 0, stream>>>(hbuf, w2t, b2, BTOT, NEMB, 4 * NEMB,
                                              xres, out, nullptr, nullptr, nullptr);
}

// Round 11
// 492.239 us; speedup vs baseline: 1.0018x; 1.0018x over previous
//
#include <hip/hip_runtime.h>

#define NEMB 1024
#define NH 16
#define HD 64
#define TT 2048
#define BTOT 4096  // B*T

typedef unsigned short u16;
typedef __bf16 bf16_t;
typedef bf16_t bf16x8 __attribute__((ext_vector_type(8)));
typedef float f32x4 __attribute__((ext_vector_type(4)));
typedef u16 u16x4 __attribute__((ext_vector_type(4)));

typedef const __attribute__((address_space(1))) void* gvp;
typedef __attribute__((address_space(3))) void* lvp;

static __device__ __forceinline__ u16 f2bf(float f) {
  unsigned u = __builtin_bit_cast(unsigned, f);
  u += 0x7fffu + ((u >> 16) & 1u);
  return (u16)(u >> 16);
}

// ---------------- fp32 -> bf16 (no transpose) ----------------
__global__ void cvt_bf16_k(const float* __restrict__ in, u16* __restrict__ out, int n4) {
  int i = blockIdx.x * blockDim.x + threadIdx.x;
  if (i >= n4) return;
  float4 f = ((const float4*)in)[i];
  u16x4 o = { f2bf(f.x), f2bf(f.y), f2bf(f.z), f2bf(f.w) };
  ((u16x4*)out)[i] = o;
}

// ---------------- fp32 [R][C] -> bf16 [C][R] ----------------
__global__ void transpose_cvt_k(const float* __restrict__ in, u16* __restrict__ out, int R, int C) {
  __shared__ float tile[32][33];
  int bx = blockIdx.x, by = blockIdx.y;
  int tx = threadIdx.x, ty = threadIdx.y;
  #pragma unroll
  for (int j = 0; j < 32; j += 8)
    tile[ty + j][tx] = in[(size_t)(by * 32 + ty + j) * C + bx * 32 + tx];
  __syncthreads();
  #pragma unroll
  for (int j = 0; j < 32; j += 8)
    out[(size_t)(bx * 32 + ty + j) * R + by * 32 + tx] = f2bf(tile[tx][ty + j]);
}

// ---------------- GEMM: C = A[M,K] * Bt[N,K]^T + bias, fused epilogues ----------------
// EPI 0: QKV -> scatter q[b,h,t,d], k[b,h,t,d], vt[b,h,d,t] (bf16)
// EPI 1: bias + relu -> bf16 o0[M,N]
// EPI 2: bias + residual(res fp32) -> fp32 outf[M,N]
template<int EPI>
__global__ void gemm_bt(const u16* __restrict__ A, const u16* __restrict__ Bt,
                        const float* __restrict__ bias, int M, int N, int K,
                        const float* __restrict__ res, float* __restrict__ outf,
                        u16* __restrict__ o0, u16* __restrict__ o1, u16* __restrict__ o2)
{
  __shared__ u16 As[128 * 32];
  __shared__ u16 Bs[128 * 32];
  const int tid = threadIdx.x;
  const int wave = tid >> 6, lane = tid & 63;
  const int l16 = lane & 15, lq = lane >> 4;
  const int row0 = blockIdx.x * 128, col0 = blockIdx.y * 128;
  const int wm = (wave >> 1) * 64, wn = (wave & 1) * 64;
  f32x4 acc[4][4] = {};

  for (int k0 = 0; k0 < K; k0 += 32) {
    #pragma unroll
    for (int c = 0; c < 2; ++c) {
      int li = c * 256 + wave * 64 + lane;
      const u16* ga = A  + (size_t)(row0 + (li >> 2)) * K + k0 + (li & 3) * 8;
      const u16* gb = Bt + (size_t)(col0 + (li >> 2)) * K + k0 + (li & 3) * 8;
      __builtin_amdgcn_global_load_lds((gvp)ga, (lvp)&As[(c * 256 + wave * 64) * 8], 16, 0, 0);
      __builtin_amdgcn_global_load_lds((gvp)gb, (lvp)&Bs[(c * 256 + wave * 64) * 8], 16, 0, 0);
    }
    __syncthreads();
    bf16x8 af[4], bfr[4];
    #pragma unroll
    for (int i = 0; i < 4; ++i) af[i]  = *(const bf16x8*)&As[(wm + i * 16 + l16) * 32 + lq * 8];
    #pragma unroll
    for (int j = 0; j < 4; ++j) bfr[j] = *(const bf16x8*)&Bs[(wn + j * 16 + l16) * 32 + lq * 8];
    #pragma unroll
    for (int i = 0; i < 4; ++i)
      #pragma unroll
      for (int j = 0; j < 4; ++j)
        acc[i][j] = __builtin_amdgcn_mfma_f32_16x16x32_bf16(af[i], bfr[j], acc[i][j], 0, 0, 0);
    __syncthreads();
  }

  #pragma unroll
  for (int i = 0; i < 4; ++i)
    #pragma unroll
    for (int j = 0; j < 4; ++j)
      #pragma unroll
      for (int r = 0; r < 4; ++r) {
        int grow = row0 + wm + i * 16 + lq * 4 + r;
        int gcol = col0 + wn + j * 16 + l16;
        float v = acc[i][j][r] + bias[gcol];
        if constexpr (EPI == 0) {
          int b = grow >> 11, t = grow & 2047;
          int sec = gcol >> 10, rem = gcol & 1023;
          int h = rem >> 6, d = rem & 63;
          u16 bits = f2bf(v);
          size_t bh = (size_t)(b * NH + h);
          if (sec == 0)      o0[(bh * TT + t) * HD + d] = bits;
          else if (sec == 1) o1[(bh * TT + t) * HD + d] = bits;
          else               o2[(bh * HD + d) * TT + t] = bits;
        } else if constexpr (EPI == 1) {
          v = fmaxf(v, 0.f);
          o0[(size_t)grow * N + gcol] = f2bf(v);
        } else {
          size_t idx = (size_t)grow * N + gcol;
          outf[idx] = v + res[idx];
        }
      }
}

// ---------------- flash attention + residual ----------------
// grid: 1024 blocks (1-D, XCD-swizzled), 256 threads = 4 waves, 16 q-rows/wave.
// SWAPPED QK^T: sacc = mfma(K, Q) -> lane holds S^T[kv=lq*4+r+16n][q=l16].
// Softmax is ONE chain per iter: in-register reduce over 16 kv + 2 shfl_xor
// (lanes sharing l16 differ only in lq -> xor 16/32). P LDS round-trip
// re-indexes q to the lq*4+r domain for the (unchanged) PV step.
__global__ void __launch_bounds__(256, 4)
attn_k(const u16* __restrict__ qb, const u16* __restrict__ kb,
       const u16* __restrict__ vtb, const float* __restrict__ x,
       float* __restrict__ xres, u16* __restrict__ xresbf)
{
  __shared__ u16 P[4][16 * 72];  // per-wave P tile [16 q-rows][stride 72 u16]
  const int id = blockIdx.x;
  const int xcd = id & 7, r8 = id >> 3;
  const int bh = xcd * 4 + (r8 >> 5);
  const int xq = 31 - (r8 & 31);           // longest-first within XCD
  const int b = bh >> 4, h = bh & 15;
  const int tid = threadIdx.x, wave = tid >> 6, lane = tid & 63;
  const int l16 = lane & 15, lq = lane >> 4;
  const u16* qh = qb + (size_t)bh * TT * HD;
  const u16* kh = kb + (size_t)bh * TT * HD;
  const u16* vh = vtb + (size_t)bh * HD * TT;
  const int q0 = (xq * 4 + wave) * 16;

  bf16x8 qf[2];
  #pragma unroll
  for (int kd = 0; kd < 2; ++kd)
    qf[kd] = *(const bf16x8*)&qh[(q0 + l16) * HD + kd * 32 + lq * 8];

  f32x4 oacc[4] = {};
  float mrow = -1e30f, lrow = 0.f;   // softmax state for q = q0 + l16
  const int qg = q0 + l16;

  const int nkv = (q0 >> 6) + 1;
  u16* Pw = P[wave];

  for (int kv = 0; kv < nkv; ++kv) {
    const int kv0 = kv * 64;
    const bool diag = (kv0 + 63 > q0);

    // QK^T (swapped): batch all 8 K-fragment loads, then 8 MFMA
    bf16x8 kf[8];
    #pragma unroll
    for (int n = 0; n < 4; ++n)
      #pragma unroll
      for (int kd = 0; kd < 2; ++kd)
        kf[n * 2 + kd] = *(const bf16x8*)&kh[(kv0 + n * 16 + l16) * HD + kd * 32 + lq * 8];
    f32x4 sacc[4] = {};
    #pragma unroll
    for (int n = 0; n < 4; ++n)
      #pragma unroll
      for (int kd = 0; kd < 2; ++kd)
        sacc[n] = __builtin_amdgcn_mfma_f32_16x16x32_bf16(kf[n * 2 + kd], qf[kd], sacc[n], 0, 0, 0);

    // V first half issued early: latency hides under softmax + P round-trip
    bf16x8 vf0[4];
    #pragma unroll
    for (int nd = 0; nd < 4; ++nd)
      vf0[nd] = *(const bf16x8*)&vh[(nd * 16 + l16) * TT + kv0 + lq * 8];

    // --- single-chain online softmax (lane owns 16 kv-values of row q=l16) ---
    float smax = -1e30f;
    #pragma unroll
    for (int n = 0; n < 4; ++n)
      #pragma unroll
      for (int r = 0; r < 4; ++r) {
        float s = sacc[n][r] * 0.125f;
        if (diag && (kv0 + n * 16 + lq * 4 + r) > qg) s = -1e30f;
        sacc[n][r] = s;
        smax = fmaxf(smax, s);
      }
    smax = fmaxf(smax, __shfl_xor(smax, 16, 64));
    smax = fmaxf(smax, __shfl_xor(smax, 32, 64));
    const float mnew = fmaxf(mrow, smax);
    const float scl = __expf(mrow - mnew);
    float rsum = 0.f;
    #pragma unroll
    for (int n = 0; n < 4; ++n)
      #pragma unroll
      for (int r = 0; r < 4; ++r) {
        float p = __expf(sacc[n][r] - mnew);
        sacc[n][r] = p;
        rsum += p;
      }
    rsum += __shfl_xor(rsum, 16, 64);
    rsum += __shfl_xor(rsum, 32, 64);
    mrow = mnew;
    lrow = lrow * scl + rsum;

    // broadcast rescale factors into oacc's q = lq*4+r domain (lanes 0..15 hold q-state)
    float sclr[4];
    #pragma unroll
    for (int r = 0; r < 4; ++r) sclr[r] = __shfl(scl, lq * 4 + r, 64);
    #pragma unroll
    for (int nd = 0; nd < 4; ++nd)
      #pragma unroll
      for (int r = 0; r < 4; ++r) oacc[nd][r] *= sclr[r];

    // P -> LDS at [q=l16][kv], packed b32 stores
    #pragma unroll
    for (int n = 0; n < 4; ++n)
      #pragma unroll
      for (int i = 0; i < 2; ++i) {
        unsigned pk = (unsigned)f2bf(sacc[n][2 * i]) | ((unsigned)f2bf(sacc[n][2 * i + 1]) << 16);
        *(unsigned*)&Pw[l16 * 72 + n * 16 + lq * 4 + 2 * i] = pk;
      }

    // V second half
    bf16x8 vf1[4];
    #pragma unroll
    for (int nd = 0; nd < 4; ++nd)
      vf1[nd] = *(const bf16x8*)&vh[(nd * 16 + l16) * TT + kv0 + 32 + lq * 8];

    // PV (unchanged): A = P rows (q=l16), B = V^T -> oacc[q=lq*4+r][d=nd*16+l16]
    bf16x8 pf0 = *(const bf16x8*)&Pw[l16 * 72 + lq * 8];
    #pragma unroll
    for (int nd = 0; nd < 4; ++nd)
      oacc[nd] = __builtin_amdgcn_mfma_f32_16x16x32_bf16(pf0, vf0[nd], oacc[nd], 0, 0, 0);
    bf16x8 pf1 = *(const bf16x8*)&Pw[l16 * 72 + 32 + lq * 8];
    #pragma unroll
    for (int nd = 0; nd < 4; ++nd)
      oacc[nd] = __builtin_amdgcn_mfma_f32_16x16x32_bf16(pf1, vf1[nd], oacc[nd], 0, 0, 0);
  }

  // epilogue: pull per-row 1/l from the l16-domain lanes
  float invr[4];
  #pragma unroll
  for (int r = 0; r < 4; ++r) invr[r] = 1.f / __shfl(lrow, lq * 4 + r, 64);
  #pragma unroll
  for (int r = 0; r < 4; ++r) {
    const int t = q0 + lq * 4 + r;
    const size_t rowbase = ((size_t)b * TT + t) * NEMB + h * HD;
    #pragma unroll
    for (int nd = 0; nd < 4; ++nd) {
      size_t idx = rowbase + nd * 16 + l16;
      float v = oacc[nd][r] * invr[r] + x[idx];
      xres[idx] = v;
      xresbf[idx] = f2bf(v);
    }
  }
}

extern "C" void kernel_launch(void* const* d_in, const int* in_sizes, int n_in,
                              void* d_out, int out_size, void* d_ws, size_t ws_size,
                              hipStream_t stream) {
  const float* x    = (const float*)d_in[0];
  const float* Wqkv = (const float*)d_in[1];
  const float* bqkv = (const float*)d_in[2];
  const float* W1   = (const float*)d_in[3];
  const float* b1   = (const float*)d_in[4];
  const float* W2   = (const float*)d_in[5];
  const float* b2   = (const float*)d_in[6];
  float* out = (float*)d_out;

  char* ws = (char*)d_ws;
  u16* x_bf   = (u16*)(ws);                         // 4096*1024
  u16* wqkvt  = (u16*)(ws + 8388608);               // 3072*1024
  u16* w1t    = (u16*)(ws + 14680064);              // 4096*1024
  u16* w2t    = (u16*)(ws + 23068672);              // 1024*4096
  u16* qbuf   = (u16*)(ws + 31457280);              // 2*16*2048*64
  u16* kbuf   = (u16*)(ws + 39845888);
  u16* vtbuf  = (u16*)(ws + 48234496);
  float* xres = (float*)(ws + 56623104);            // 4096*1024 fp32
  u16* xresbf = (u16*)(ws + 73400320);              // 4096*1024
  u16* hbuf   = (u16*)(ws + 81788928);              // 4096*4096

  // conversions
  cvt_bf16_k<<<4096, 256, 0, stream>>>(x, x_bf, 1048576);
  transpose_cvt_k<<<dim3(96, 32),  dim3(32, 8), 0, stream>>>(Wqkv, wqkvt, 1024, 3072);
  transpose_cvt_k<<<dim3(128, 32), dim3(32, 8), 0, stream>>>(W1, w1t, 1024, 4096);
  transpose_cvt_k<<<dim3(32, 128), dim3(32, 8), 0, stream>>>(W2, w2t, 4096, 1024);

  // QKV projection
  gemm_bt<0><<<dim3(32, 24), 256, 0, stream>>>(x_bf, wqkvt, bqkv, BTOT, 3 * NEMB, NEMB,
                                               nullptr, nullptr, qbuf, kbuf, vtbuf);
  // attention + residual
  attn_k<<<1024, 256, 0, stream>>>(qbuf, kbuf, vtbuf, x, xres, xresbf);
  // MLP
  gemm_bt<1><<<dim3(32, 32), 256, 0, stream>>>(xresbf, w1t, b1, BTOT, 4 * NEMB, NEMB,
                                               nullptr, nullptr, hbuf, nullptr, nullptr);
  gemm_bt<2><<<dim3(32, 8), 256, 0, stream>>>(hbuf, w2t, b2, BTOT, NEMB, 4 * NEMB,
                                              xres, out, nullptr, nullptr, nullptr);
}

// Round 12
// 422.420 us; speedup vs baseline: 1.1674x; 1.1653x over previous
//
#include <hip/hip_runtime.h>

#define NEMB 1024
#define NH 16
#define HD 64
#define TT 2048
#define BTOT 4096  // B*T

typedef unsigned short u16;
typedef __bf16 bf16_t;
typedef bf16_t bf16x8 __attribute__((ext_vector_type(8)));
typedef float f32x4 __attribute__((ext_vector_type(4)));
typedef u16 u16x4 __attribute__((ext_vector_type(4)));

typedef const __attribute__((address_space(1))) void* gvp;
typedef __attribute__((address_space(3))) void* lvp;

static __device__ __forceinline__ u16 f2bf(float f) {
  unsigned u = __builtin_bit_cast(unsigned, f);
  u += 0x7fffu + ((u >> 16) & 1u);
  return (u16)(u >> 16);
}

// ---------------- fp32 -> bf16 (no transpose) ----------------
__global__ void cvt_bf16_k(const float* __restrict__ in, u16* __restrict__ out, int n4) {
  int i = blockIdx.x * blockDim.x + threadIdx.x;
  if (i >= n4) return;
  float4 f = ((const float4*)in)[i];
  u16x4 o = { f2bf(f.x), f2bf(f.y), f2bf(f.z), f2bf(f.w) };
  ((u16x4*)out)[i] = o;
}

// ---------------- fp32 [R][C] -> bf16 [C][R] ----------------
__global__ void transpose_cvt_k(const float* __restrict__ in, u16* __restrict__ out, int R, int C) {
  __shared__ float tile[32][33];
  int bx = blockIdx.x, by = blockIdx.y;
  int tx = threadIdx.x, ty = threadIdx.y;
  #pragma unroll
  for (int j = 0; j < 32; j += 8)
    tile[ty + j][tx] = in[(size_t)(by * 32 + ty + j) * C + bx * 32 + tx];
  __syncthreads();
  #pragma unroll
  for (int j = 0; j < 32; j += 8)
    out[(size_t)(bx * 32 + ty + j) * R + by * 32 + tx] = f2bf(tile[tx][ty + j]);
}

// ---------------- GEMM: C = A[M,K] * Bt[N,K]^T + bias, fused epilogues ----------------
// EPI 0: QKV -> scatter q[b,h,t,d], k[b,h,t,d], vt[b,h,d,t] (bf16)
// EPI 1: bias + relu -> bf16 o0[M,N]
// EPI 2: bias + residual(res fp32) -> fp32 outf[M,N]
template<int EPI>
__global__ void gemm_bt(const u16* __restrict__ A, const u16* __restrict__ Bt,
                        const float* __restrict__ bias, int M, int N, int K,
                        const float* __restrict__ res, float* __restrict__ outf,
                        u16* __restrict__ o0, u16* __restrict__ o1, u16* __restrict__ o2)
{
  __shared__ u16 As[128 * 32];
  __shared__ u16 Bs[128 * 32];
  const int tid = threadIdx.x;
  const int wave = tid >> 6, lane = tid & 63;
  const int l16 = lane & 15, lq = lane >> 4;
  const int row0 = blockIdx.x * 128, col0 = blockIdx.y * 128;
  const int wm = (wave >> 1) * 64, wn = (wave & 1) * 64;
  f32x4 acc[4][4] = {};

  for (int k0 = 0; k0 < K; k0 += 32) {
    #pragma unroll
    for (int c = 0; c < 2; ++c) {
      int li = c * 256 + wave * 64 + lane;
      const u16* ga = A  + (size_t)(row0 + (li >> 2)) * K + k0 + (li & 3) * 8;
      const u16* gb = Bt + (size_t)(col0 + (li >> 2)) * K + k0 + (li & 3) * 8;
      __builtin_amdgcn_global_load_lds((gvp)ga, (lvp)&As[(c * 256 + wave * 64) * 8], 16, 0, 0);
      __builtin_amdgcn_global_load_lds((gvp)gb, (lvp)&Bs[(c * 256 + wave * 64) * 8], 16, 0, 0);
    }
    __syncthreads();
    bf16x8 af[4], bfr[4];
    #pragma unroll
    for (int i = 0; i < 4; ++i) af[i]  = *(const bf16x8*)&As[(wm + i * 16 + l16) * 32 + lq * 8];
    #pragma unroll
    for (int j = 0; j < 4; ++j) bfr[j] = *(const bf16x8*)&Bs[(wn + j * 16 + l16) * 32 + lq * 8];
    #pragma unroll
    for (int i = 0; i < 4; ++i)
      #pragma unroll
      for (int j = 0; j < 4; ++j)
        acc[i][j] = __builtin_amdgcn_mfma_f32_16x16x32_bf16(af[i], bfr[j], acc[i][j], 0, 0, 0);
    __syncthreads();
  }

  #pragma unroll
  for (int i = 0; i < 4; ++i)
    #pragma unroll
    for (int j = 0; j < 4; ++j)
      #pragma unroll
      for (int r = 0; r < 4; ++r) {
        int grow = row0 + wm + i * 16 + lq * 4 + r;
        int gcol = col0 + wn + j * 16 + l16;
        float v = acc[i][j][r] + bias[gcol];
        if constexpr (EPI == 0) {
          int b = grow >> 11, t = grow & 2047;
          int sec = gcol >> 10, rem = gcol & 1023;
          int h = rem >> 6, d = rem & 63;
          u16 bits = f2bf(v);
          size_t bh = (size_t)(b * NH + h);
          if (sec == 0)      o0[(bh * TT + t) * HD + d] = bits;
          else if (sec == 1) o1[(bh * TT + t) * HD + d] = bits;
          else               o2[(bh * HD + d) * TT + t] = bits;
        } else if constexpr (EPI == 1) {
          v = fmaxf(v, 0.f);
          o0[(size_t)grow * N + gcol] = f2bf(v);
        } else {
          size_t idx = (size_t)grow * N + gcol;
          outf[idx] = v + res[idx];
        }
      }
}

// ---------------- flash attention + residual ----------------
// 1024 blocks, 4 waves, 16 q-rows/wave. Swapped QK^T (lane holds S^T, q=l16).
// K-fragments double-buffered in registers (prefetch kv+1 during body kv);
// V loads issued before softmax. launch_bounds(256,2) frees the allocator.
// Per-CU length balance: head-slot h on CU c gets xq so that sum(nkv)=66 all c.
__global__ void __launch_bounds__(256, 2)
attn_k(const u16* __restrict__ qb, const u16* __restrict__ kb,
       const u16* __restrict__ vtb, const float* __restrict__ x,
       float* __restrict__ xres, u16* __restrict__ xresbf)
{
  __shared__ u16 P[4][16 * 72];  // per-wave P tile [16 q-rows][stride 72 u16]
  const int id = blockIdx.x;
  const int xcd = id & 7, r8 = id >> 3;
  const int hslot = r8 >> 5, c = r8 & 31;
  const int bh = xcd * 4 + hslot;
  int xq;
  if      (hslot == 0) xq = 31 - c;
  else if (hslot == 1) xq = c;
  else if (hslot == 2) xq = (47 - c) & 31;
  else                 xq = (c + 16) & 31;
  const int b = bh >> 4, h = bh & 15;
  const int tid = threadIdx.x, wave = tid >> 6, lane = tid & 63;
  const int l16 = lane & 15, lq = lane >> 4;
  const u16* qh = qb + (size_t)bh * TT * HD;
  const u16* kh = kb + (size_t)bh * TT * HD;
  const u16* vh = vtb + (size_t)bh * HD * TT;
  const int q0 = (xq * 4 + wave) * 16;

  bf16x8 qf[2];
  #pragma unroll
  for (int kd = 0; kd < 2; ++kd)
    qf[kd] = *(const bf16x8*)&qh[(q0 + l16) * HD + kd * 32 + lq * 8];

  f32x4 oacc[4] = {};
  float mrow = -1e30f, lrow = 0.f;   // softmax state for q = q0 + l16
  const int qg = q0 + l16;

  const int nkv = (q0 >> 6) + 1;
  u16* Pw = P[wave];

  // K-fragment loader (static indices after inlining)
  auto loadk = [&](bf16x8 (&kf)[8], int kv0) {
    #pragma unroll
    for (int n = 0; n < 4; ++n)
      #pragma unroll
      for (int kd = 0; kd < 2; ++kd)
        kf[n * 2 + kd] = *(const bf16x8*)&kh[(kv0 + n * 16 + l16) * HD + kd * 32 + lq * 8];
  };

  // one KV-block body: QK^T (swapped) -> V issue -> softmax -> P roundtrip -> PV
  auto body = [&](const bf16x8 (&kf)[8], int kv0) {
    const bool diag = (kv0 + 63 > q0);
    f32x4 sacc[4] = {};
    #pragma unroll
    for (int n = 0; n < 4; ++n)
      #pragma unroll
      for (int kd = 0; kd < 2; ++kd)
        sacc[n] = __builtin_amdgcn_mfma_f32_16x16x32_bf16(kf[n * 2 + kd], qf[kd], sacc[n], 0, 0, 0);

    // all 8 V loads issued before softmax -> latency hides under it
    bf16x8 vf[8];
    #pragma unroll
    for (int nd = 0; nd < 4; ++nd) {
      vf[nd]     = *(const bf16x8*)&vh[(nd * 16 + l16) * TT + kv0 + lq * 8];
      vf[4 + nd] = *(const bf16x8*)&vh[(nd * 16 + l16) * TT + kv0 + 32 + lq * 8];
    }

    // single-chain online softmax (lane owns 16 kv-values of row q=l16)
    float smax = -1e30f;
    #pragma unroll
    for (int n = 0; n < 4; ++n)
      #pragma unroll
      for (int r = 0; r < 4; ++r) {
        float s = sacc[n][r] * 0.125f;
        if (diag && (kv0 + n * 16 + lq * 4 + r) > qg) s = -1e30f;
        sacc[n][r] = s;
        smax = fmaxf(smax, s);
      }
    smax = fmaxf(smax, __shfl_xor(smax, 16, 64));
    smax = fmaxf(smax, __shfl_xor(smax, 32, 64));
    const float mnew = fmaxf(mrow, smax);
    const float scl = __expf(mrow - mnew);
    float rsum = 0.f;
    #pragma unroll
    for (int n = 0; n < 4; ++n)
      #pragma unroll
      for (int r = 0; r < 4; ++r) {
        float p = __expf(sacc[n][r] - mnew);
        sacc[n][r] = p;
        rsum += p;
      }
    rsum += __shfl_xor(rsum, 16, 64);
    rsum += __shfl_xor(rsum, 32, 64);
    mrow = mnew;
    lrow = lrow * scl + rsum;

    // broadcast rescale factors into oacc's q = lq*4+r domain
    float sclr[4];
    #pragma unroll
    for (int r = 0; r < 4; ++r) sclr[r] = __shfl(scl, lq * 4 + r, 64);
    #pragma unroll
    for (int nd = 0; nd < 4; ++nd)
      #pragma unroll
      for (int r = 0; r < 4; ++r) oacc[nd][r] *= sclr[r];

    // P -> LDS at [q=l16][kv], packed b32 stores
    #pragma unroll
    for (int n = 0; n < 4; ++n)
      #pragma unroll
      for (int i = 0; i < 2; ++i) {
        unsigned pk = (unsigned)f2bf(sacc[n][2 * i]) | ((unsigned)f2bf(sacc[n][2 * i + 1]) << 16);
        *(unsigned*)&Pw[l16 * 72 + n * 16 + lq * 4 + 2 * i] = pk;
      }

    // PV: A = P rows (q=l16), B = V^T -> oacc[q=lq*4+r][d=nd*16+l16]
    bf16x8 pf0 = *(const bf16x8*)&Pw[l16 * 72 + lq * 8];
    #pragma unroll
    for (int nd = 0; nd < 4; ++nd)
      oacc[nd] = __builtin_amdgcn_mfma_f32_16x16x32_bf16(pf0, vf[nd], oacc[nd], 0, 0, 0);
    bf16x8 pf1 = *(const bf16x8*)&Pw[l16 * 72 + 32 + lq * 8];
    #pragma unroll
    for (int nd = 0; nd < 4; ++nd)
      oacc[nd] = __builtin_amdgcn_mfma_f32_16x16x32_bf16(pf1, vf[4 + nd], oacc[nd], 0, 0, 0);
  };

  // software-pipelined loop: prefetch next K tile into the other buffer
  bf16x8 kfA[8], kfB[8];
  loadk(kfA, 0);
  for (int kv = 0; kv < nkv; ) {
    if (kv + 1 < nkv) loadk(kfB, (kv + 1) * 64);
    body(kfA, kv * 64);
    ++kv; if (kv == nkv) break;
    if (kv + 1 < nkv) loadk(kfA, (kv + 1) * 64);
    body(kfB, kv * 64);
    ++kv;
  }

  // epilogue: pull per-row 1/l from the l16-domain lanes
  float invr[4];
  #pragma unroll
  for (int r = 0; r < 4; ++r) invr[r] = 1.f / __shfl(lrow, lq * 4 + r, 64);
  #pragma unroll
  for (int r = 0; r < 4; ++r) {
    const int t = q0 + lq * 4 + r;
    const size_t rowbase = ((size_t)b * TT + t) * NEMB + h * HD;
    #pragma unroll
    for (int nd = 0; nd < 4; ++nd) {
      size_t idx = rowbase + nd * 16 + l16;
      float v = oacc[nd][r] * invr[r] + x[idx];
      xres[idx] = v;
      xresbf[idx] = f2bf(v);
    }
  }
}

extern "C" void kernel_launch(void* const* d_in, const int* in_sizes, int n_in,
                              void* d_out, int out_size, void* d_ws, size_t ws_size,
                              hipStream_t stream) {
  const float* x    = (const float*)d_in[0];
  const float* Wqkv = (const float*)d_in[1];
  const float* bqkv = (const float*)d_in[2];
  const float* W1   = (const float*)d_in[3];
  const float* b1   = (const float*)d_in[4];
  const float* W2   = (const float*)d_in[5];
  const float* b2   = (const float*)d_in[6];
  float* out = (float*)d_out;

  char* ws = (char*)d_ws;
  u16* x_bf   = (u16*)(ws);                         // 4096*1024
  u16* wqkvt  = (u16*)(ws + 8388608);               // 3072*1024
  u16* w1t    = (u16*)(ws + 14680064);              // 4096*1024
  u16* w2t    = (u16*)(ws + 23068672);              // 1024*4096
  u16* qbuf   = (u16*)(ws + 31457280);              // 2*16*2048*64
  u16* kbuf   = (u16*)(ws + 39845888);
  u16* vtbuf  = (u16*)(ws + 48234496);
  float* xres = (float*)(ws + 56623104);            // 4096*1024 fp32
  u16* xresbf = (u16*)(ws + 73400320);              // 4096*1024
  u16* hbuf   = (u16*)(ws + 81788928);              // 4096*4096

  // conversions
  cvt_bf16_k<<<4096, 256, 0, stream>>>(x, x_bf, 1048576);
  transpose_cvt_k<<<dim3(96, 32),  dim3(32, 8), 0, stream>>>(Wqkv, wqkvt, 1024, 3072);
  transpose_cvt_k<<<dim3(128, 32), dim3(32, 8), 0, stream>>>(W1, w1t, 1024, 4096);
  transpose_cvt_k<<<dim3(32, 128), dim3(32, 8), 0, stream>>>(W2, w2t, 4096, 1024);

  // QKV projection
  gemm_bt<0><<<dim3(32, 24), 256, 0, stream>>>(x_bf, wqkvt, bqkv, BTOT, 3 * NEMB, NEMB,
                                               nullptr, nullptr, qbuf, kbuf, vtbuf);
  // attention + residual
  attn_k<<<1024, 256, 0, stream>>>(qbuf, kbuf, vtbuf, x, xres, xresbf);
  // MLP
  gemm_bt<1><<<dim3(32, 32), 256, 0, stream>>>(xresbf, w1t, b1, BTOT, 4 * NEMB, NEMB,
                                               nullptr, nullptr, hbuf, nullptr, nullptr);
  gemm_bt<2><<<dim3(32, 8), 256, 0, stream>>>(hbuf, w2t, b2, BTOT, NEMB, 4 * NEMB,
                                              xres, out, nullptr, nullptr, nullptr);
}